// Round 1
// baseline (918.868 us; speedup 1.0000x reference)
//
#include <hip/hip_runtime.h>

typedef __bf16 bf16x8 __attribute__((ext_vector_type(8)));
typedef float floatx4 __attribute__((ext_vector_type(4)));

#define XS 136    // LDS row stride in bf16 elements (272 B -> 2-way bank aliasing = free)
#define ROWS 64   // rows per block

__device__ __forceinline__ unsigned short f32_bf16(float f) {
    union { float f; unsigned int u; } c; c.f = f;
    return (unsigned short)((c.u + 0x7fffu + ((c.u >> 16) & 1u)) >> 16);  // RNE, finite inputs
}

// w1 -> MFMA B-fragment order, hidden-col mapping h(nt,l15) = l15*32 + nt.
// frag f = (e*32+nt)*4+ks ; lane (quad,l15) holds B[k=quad*8+j][n=l15] = w1[e][h][k]
__global__ __launch_bounds__(256) void prep_w1_frag(const float* __restrict__ w1,
                                                    unsigned short* __restrict__ wbf) {
    int g    = blockIdx.x * 256 + threadIdx.x;   // 64 blocks -> 16384 threads
    int lane = g & 63;
    int frag = g >> 6;                            // 0..255
    int ks   = frag & 3;
    int nt   = (frag >> 2) & 31;
    int e    = frag >> 7;
    int l15  = lane & 15;
    int quad = lane >> 4;
    int h    = l15 * 32 + nt;
    const float* src = w1 + ((e * 512 + h) * 128 + ks * 32 + quad * 8);
    unsigned short* dst = wbf + (long)g * 8;      // 16 B/lane, contiguous per wave
    #pragma unroll
    for (int j = 0; j < 8; ++j) dst[j] = f32_bf16(src[j]);
}

// One workgroup = 64 rows x all 1024 hidden cols. Wave w: expert e = w>>1,
// nt-half slice = w&1, 4 register-resident m-tiles (afrag[4][4] = 64 VGPR,
// outp[4][4][2] = 32 VGPR -> true register residency within the 128-VGPR cap).
// launch_bounds(256,4): 4 blocks/CU = 16 waves/CU (50% occupancy) to hide
// L2 weight-load latency. Weight L2 traffic: 2048 blocks x 256 KiB = 512 MiB.
__global__ __launch_bounds__(256, 4) void moe_fused(
    const float* __restrict__ x,
    const unsigned short* __restrict__ wbf,   // fragment-ordered bf16 w1
    const float* __restrict__ b1,             // [2][512]
    const float* __restrict__ w2,             // [2][2][512]
    const float* __restrict__ b2,             // [2][2]
    const float* __restrict__ protos,         // [2][128]
    float* __restrict__ out)                  // [B][2]
{
    __shared__ unsigned short xs[ROWS * XS];  // 17408 B
    __shared__ float out_s[2][ROWS][2][2];    // [slice][row][e][o]  2048 B
    __shared__ int   t_s[ROWS];               // 256 B  -> 19712 B total

    const int tid   = threadIdx.x;
    const int lane  = tid & 63;
    const int wave  = tid >> 6;
    const int quad  = lane >> 4;
    const int l15   = lane & 15;
    const int slice = wave & 1;               // nt-half 0/1
    const int e     = wave >> 1;              // expert
    const long rowbase = (long)blockIdx.x * ROWS;

    // ---- routing: t = (d1 < d0) via sign of sum_c (p0-p1)*(0.5*(p0+p1)-x), fp64 ----
    // identical arithmetic/order to the verified version (2 threads per row)
    if (tid < 2 * ROWS) {
        int r   = tid >> 1;
        int sub = tid & 1;
        const float* xr = x + (rowbase + r) * 128 + sub * 64;
        const float* p0 = protos + sub * 64;
        const float* p1 = protos + 128 + sub * 64;
        double acc = 0.0;
        #pragma unroll
        for (int k = 0; k < 16; ++k) {
            float4 xv = *(const float4*)(xr + k * 4);
            float4 a  = *(const float4*)(p0 + k * 4);
            float4 b  = *(const float4*)(p1 + k * 4);
            acc += ((double)a.x - b.x) * (0.5 * ((double)a.x + b.x) - xv.x);
            acc += ((double)a.y - b.y) * (0.5 * ((double)a.y + b.y) - xv.y);
            acc += ((double)a.z - b.z) * (0.5 * ((double)a.z + b.z) - xv.z);
            acc += ((double)a.w - b.w) * (0.5 * ((double)a.w + b.w) - xv.w);
        }
        acc += __shfl_xor(acc, 1);
        if (sub == 0) t_s[r] = (acc > 0.0) ? 1 : 0;   // tie -> expert 0 (numpy argmin)
    }

    // ---- stage x tile: coalesced float4 global reads -> bf16 LDS ----
    for (int i = tid; i < ROWS * 32; i += 256) {
        int r  = i >> 5;
        int c4 = (i & 31) * 4;
        float4 v = *(const float4*)(x + (rowbase + r) * 128 + c4);
        ushort4 p;
        p.x = f32_bf16(v.x); p.y = f32_bf16(v.y);
        p.z = f32_bf16(v.z); p.w = f32_bf16(v.w);
        *(ushort4*)&xs[r * XS + c4] = p;
    }
    __syncthreads();

    // ---- A fragments: 4 m-tiles x 4 k-steps, register-resident (one-time LDS read) ----
    // A-operand layout: A[m = lane&15][k = quad*8 + j]
    bf16x8 afrag[4][4];
    #pragma unroll
    for (int mt = 0; mt < 4; ++mt) {
        int r = mt * 16 + l15;
        #pragma unroll
        for (int ks = 0; ks < 4; ++ks)
            afrag[mt][ks] = *(const bf16x8*)&xs[r * XS + ks * 32 + quad * 8];
    }

    float outp[4][4][2] = {};   // [m-tile][reg(row)][o] layer-2 partials

    // ---- main loop: 16 n-tiles (this wave's expert + nt-half), all frags read once ----
    const bf16x8* wb8 = (const bf16x8*)wbf + (long)((e * 32 + slice * 16) * 4) * 64 + lane;
    const int    coff = e * 512 + l15 * 32 + slice * 16;
    const float* b1p  = b1 + coff;
    const float* w2ap = w2 + e * 1024 + l15 * 32 + slice * 16;
    const float* w2bp = w2ap + 512;
    for (int nt = 0; nt < 16; ++nt) {
        const bf16x8* wp = wb8 + nt * 256;
        bf16x8 bf0 = wp[0];
        bf16x8 bf1 = wp[64];
        bf16x8 bf2 = wp[128];
        bf16x8 bf3 = wp[192];
        float bb  = b1p[nt];
        float w2a = w2ap[nt];
        float w2b = w2bp[nt];
        #pragma unroll
        for (int mt = 0; mt < 4; ++mt) {
            floatx4 c = {bb, bb, bb, bb};   // bias folded into accumulator init
            c = __builtin_amdgcn_mfma_f32_16x16x32_bf16(afrag[mt][0], bf0, c, 0, 0, 0);
            c = __builtin_amdgcn_mfma_f32_16x16x32_bf16(afrag[mt][1], bf1, c, 0, 0, 0);
            c = __builtin_amdgcn_mfma_f32_16x16x32_bf16(afrag[mt][2], bf2, c, 0, 0, 0);
            c = __builtin_amdgcn_mfma_f32_16x16x32_bf16(afrag[mt][3], bf3, c, 0, 0, 0);
            #pragma unroll
            for (int rg = 0; rg < 4; ++rg) {
                float h = fmaxf(c[rg], 0.0f);
                outp[mt][rg][0] = fmaf(h, w2a, outp[mt][rg][0]);
                outp[mt][rg][1] = fmaf(h, w2b, outp[mt][rg][1]);
            }
        }
    }

    // ---- reduce layer-2 partials across the 16 column-lanes, write slice buffer ----
    #pragma unroll
    for (int mt = 0; mt < 4; ++mt)
        #pragma unroll
        for (int rg = 0; rg < 4; ++rg) {
            float v0 = outp[mt][rg][0];
            float v1 = outp[mt][rg][1];
            v0 += __shfl_xor(v0, 1);  v1 += __shfl_xor(v1, 1);
            v0 += __shfl_xor(v0, 2);  v1 += __shfl_xor(v1, 2);
            v0 += __shfl_xor(v0, 4);  v1 += __shfl_xor(v1, 4);
            v0 += __shfl_xor(v0, 8);  v1 += __shfl_xor(v1, 8);
            if (l15 == 0) {
                int r = mt * 16 + quad * 4 + rg;   // C/D: row = quad*4 + reg
                out_s[slice][r][e][0] = v0;
                out_s[slice][r][e][1] = v1;
            }
        }
    __syncthreads();

    // ---- select expert per row, combine nt-halves, add b2, coalesced store ----
    if (tid < 2 * ROWS) {
        int r  = tid >> 1;
        int o  = tid & 1;
        int te = t_s[r];
        out[(rowbase + r) * 2 + o] =
            out_s[0][r][te][o] + out_s[1][r][te][o] + b2[te * 2 + o];
    }
}

extern "C" void kernel_launch(void* const* d_in, const int* in_sizes, int n_in,
                              void* d_out, int out_size, void* d_ws, size_t ws_size,
                              hipStream_t stream) {
    const float* x      = (const float*)d_in[0];
    const float* w1     = (const float*)d_in[1];
    const float* b1     = (const float*)d_in[2];
    const float* w2     = (const float*)d_in[3];
    const float* b2     = (const float*)d_in[4];
    const float* protos = (const float*)d_in[5];
    float* out = (float*)d_out;
    unsigned short* wbf = (unsigned short*)d_ws;   // 256 KiB bf16 fragment-ordered w1

    prep_w1_frag<<<dim3(64), dim3(256), 0, stream>>>(w1, wbf);
    moe_fused<<<dim3(2048), dim3(256), 0, stream>>>(x, wbf, b1, w2, b2, protos, out);
}

// Round 2
// 421.290 us; speedup vs baseline: 2.1811x; 2.1811x over previous
//
#include <hip/hip_runtime.h>

typedef __bf16 bf16x8 __attribute__((ext_vector_type(8)));
typedef float floatx4 __attribute__((ext_vector_type(4)));

#define XS 136    // LDS row stride in bf16 elements (272 B -> 2-way bank aliasing = free)
#define ROWS 64   // rows per block

__device__ __forceinline__ unsigned short f32_bf16(float f) {
    union { float f; unsigned int u; } c; c.f = f;
    return (unsigned short)((c.u + 0x7fffu + ((c.u >> 16) & 1u)) >> 16);  // RNE, finite inputs
}

// w1 -> MFMA B-fragment order, hidden-col mapping h(nt,l15) = l15*32 + nt.
// frag f = (e*32+nt)*4+ks ; lane (quad,l15) holds B[k=quad*8+j][n=l15] = w1[e][h][k]
__global__ __launch_bounds__(256) void prep_w1_frag(const float* __restrict__ w1,
                                                    unsigned short* __restrict__ wbf) {
    int g    = blockIdx.x * 256 + threadIdx.x;   // 64 blocks -> 16384 threads
    int lane = g & 63;
    int frag = g >> 6;                            // 0..255
    int ks   = frag & 3;
    int nt   = (frag >> 2) & 31;
    int e    = frag >> 7;
    int l15  = lane & 15;
    int quad = lane >> 4;
    int h    = l15 * 32 + nt;
    const float* src = w1 + ((e * 512 + h) * 128 + ks * 32 + quad * 8);
    unsigned short* dst = wbf + (long)g * 8;      // 16 B/lane, contiguous per wave
    #pragma unroll
    for (int j = 0; j < 8; ++j) dst[j] = f32_bf16(src[j]);
}

// One workgroup = 64 rows x all 1024 hidden cols. Wave w: expert e = w>>1,
// nt-half slice = w&1, 4 register-resident m-tiles (afrag[4][4]=64 VGPR,
// outp[4][4][2]=32 VGPR, weight cur+next 32 VGPR -> ~150 natural footprint).
// __launch_bounds__(256,2): VGPR cap 256 -> allocator never spills (round-1's
// (256,4) cap of 128 caused catastrophic scratch spill: 1.7 GB scratch writes).
// Occupancy comes from the small footprint: ~3 blocks/CU = 12 waves/CU,
// LDS 19.7 KB is not a binder. Weight L2 traffic: 2048 blocks x 256 KiB = 512 MiB.
__global__ __launch_bounds__(256, 2) void moe_fused(
    const float* __restrict__ x,
    const unsigned short* __restrict__ wbf,   // fragment-ordered bf16 w1
    const float* __restrict__ b1,             // [2][512]
    const float* __restrict__ w2,             // [2][2][512]
    const float* __restrict__ b2,             // [2][2]
    const float* __restrict__ protos,         // [2][128]
    float* __restrict__ out)                  // [B][2]
{
    __shared__ unsigned short xs[ROWS * XS];  // 17408 B
    __shared__ float out_s[2][ROWS][2][2];    // [slice][row][e][o]  2048 B
    __shared__ int   t_s[ROWS];               // 256 B  -> 19712 B total

    const int tid   = threadIdx.x;
    const int lane  = tid & 63;
    const int wave  = tid >> 6;
    const int quad  = lane >> 4;
    const int l15   = lane & 15;
    const int slice = wave & 1;               // nt-half 0/1
    const int e     = wave >> 1;              // expert
    const long rowbase = (long)blockIdx.x * ROWS;

    // ---- routing: t = (d1 < d0) via sign of sum_c (p0-p1)*(0.5*(p0+p1)-x), fp64 ----
    if (tid < 2 * ROWS) {
        int r   = tid >> 1;
        int sub = tid & 1;
        const float* xr = x + (rowbase + r) * 128 + sub * 64;
        const float* p0 = protos + sub * 64;
        const float* p1 = protos + 128 + sub * 64;
        double acc = 0.0;
        #pragma unroll
        for (int k = 0; k < 16; ++k) {
            float4 xv = *(const float4*)(xr + k * 4);
            float4 a  = *(const float4*)(p0 + k * 4);
            float4 b  = *(const float4*)(p1 + k * 4);
            acc += ((double)a.x - b.x) * (0.5 * ((double)a.x + b.x) - xv.x);
            acc += ((double)a.y - b.y) * (0.5 * ((double)a.y + b.y) - xv.y);
            acc += ((double)a.z - b.z) * (0.5 * ((double)a.z + b.z) - xv.z);
            acc += ((double)a.w - b.w) * (0.5 * ((double)a.w + b.w) - xv.w);
        }
        acc += __shfl_xor(acc, 1);
        if (sub == 0) t_s[r] = (acc > 0.0) ? 1 : 0;   // tie -> expert 0 (numpy argmin)
    }

    // ---- stage x tile: coalesced float4 global reads -> bf16 LDS ----
    for (int i = tid; i < ROWS * 32; i += 256) {
        int r  = i >> 5;
        int c4 = (i & 31) * 4;
        float4 v = *(const float4*)(x + (rowbase + r) * 128 + c4);
        ushort4 p;
        p.x = f32_bf16(v.x); p.y = f32_bf16(v.y);
        p.z = f32_bf16(v.z); p.w = f32_bf16(v.w);
        *(ushort4*)&xs[r * XS + c4] = p;
    }
    __syncthreads();

    // ---- A fragments: 4 m-tiles x 4 k-steps, register-resident (one-time LDS read) ----
    // A-operand layout: A[m = lane&15][k = quad*8 + j]
    bf16x8 afrag[4][4];
    #pragma unroll
    for (int mt = 0; mt < 4; ++mt) {
        int r = mt * 16 + l15;
        #pragma unroll
        for (int ks = 0; ks < 4; ++ks)
            afrag[mt][ks] = *(const bf16x8*)&xs[r * XS + ks * 32 + quad * 8];
    }

    float outp[4][4][2] = {};   // [m-tile][reg(row)][o] layer-2 partials

    // ---- main loop: 16 n-tiles, 1-deep software pipeline on weight fragments ----
    const bf16x8* wb8 = (const bf16x8*)wbf + (long)((e * 32 + slice * 16) * 4) * 64 + lane;
    const int    coff = e * 512 + l15 * 32 + slice * 16;
    const float* b1p  = b1 + coff;
    const float* w2ap = w2 + e * 1024 + l15 * 32 + slice * 16;
    const float* w2bp = w2ap + 512;

    bf16x8 c0 = wb8[0], c1 = wb8[64], c2 = wb8[128], c3 = wb8[192];
    for (int nt = 0; nt < 16; ++nt) {
        // prefetch nt+1 (clamped: nt=15 re-reads itself, harmless, stays in-bounds)
        const bf16x8* np = wb8 + (nt < 15 ? nt + 1 : 15) * 256;
        bf16x8 n0 = np[0];
        bf16x8 n1 = np[64];
        bf16x8 n2 = np[128];
        bf16x8 n3 = np[192];
        float bb  = b1p[nt];
        float w2a = w2ap[nt];
        float w2b = w2bp[nt];
        #pragma unroll
        for (int mt = 0; mt < 4; ++mt) {
            floatx4 c = {bb, bb, bb, bb};   // bias folded into accumulator init
            c = __builtin_amdgcn_mfma_f32_16x16x32_bf16(afrag[mt][0], c0, c, 0, 0, 0);
            c = __builtin_amdgcn_mfma_f32_16x16x32_bf16(afrag[mt][1], c1, c, 0, 0, 0);
            c = __builtin_amdgcn_mfma_f32_16x16x32_bf16(afrag[mt][2], c2, c, 0, 0, 0);
            c = __builtin_amdgcn_mfma_f32_16x16x32_bf16(afrag[mt][3], c3, c, 0, 0, 0);
            #pragma unroll
            for (int rg = 0; rg < 4; ++rg) {
                float h = fmaxf(c[rg], 0.0f);
                outp[mt][rg][0] = fmaf(h, w2a, outp[mt][rg][0]);
                outp[mt][rg][1] = fmaf(h, w2b, outp[mt][rg][1]);
            }
        }
        c0 = n0; c1 = n1; c2 = n2; c3 = n3;
    }

    // ---- reduce layer-2 partials across the 16 column-lanes, write slice buffer ----
    #pragma unroll
    for (int mt = 0; mt < 4; ++mt)
        #pragma unroll
        for (int rg = 0; rg < 4; ++rg) {
            float v0 = outp[mt][rg][0];
            float v1 = outp[mt][rg][1];
            v0 += __shfl_xor(v0, 1);  v1 += __shfl_xor(v1, 1);
            v0 += __shfl_xor(v0, 2);  v1 += __shfl_xor(v1, 2);
            v0 += __shfl_xor(v0, 4);  v1 += __shfl_xor(v1, 4);
            v0 += __shfl_xor(v0, 8);  v1 += __shfl_xor(v1, 8);
            if (l15 == 0) {
                int r = mt * 16 + quad * 4 + rg;   // C/D: row = quad*4 + reg
                out_s[slice][r][e][0] = v0;
                out_s[slice][r][e][1] = v1;
            }
        }
    __syncthreads();

    // ---- select expert per row, combine nt-halves, add b2, coalesced store ----
    if (tid < 2 * ROWS) {
        int r  = tid >> 1;
        int o  = tid & 1;
        int te = t_s[r];
        out[(rowbase + r) * 2 + o] =
            out_s[0][r][te][o] + out_s[1][r][te][o] + b2[te * 2 + o];
    }
}

extern "C" void kernel_launch(void* const* d_in, const int* in_sizes, int n_in,
                              void* d_out, int out_size, void* d_ws, size_t ws_size,
                              hipStream_t stream) {
    const float* x      = (const float*)d_in[0];
    const float* w1     = (const float*)d_in[1];
    const float* b1     = (const float*)d_in[2];
    const float* w2     = (const float*)d_in[3];
    const float* b2     = (const float*)d_in[4];
    const float* protos = (const float*)d_in[5];
    float* out = (float*)d_out;
    unsigned short* wbf = (unsigned short*)d_ws;   // 256 KiB bf16 fragment-ordered w1

    prep_w1_frag<<<dim3(64), dim3(256), 0, stream>>>(w1, wbf);
    moe_fused<<<dim3(2048), dim3(256), 0, stream>>>(x, wbf, b1, w2, b2, protos, out);
}

// Round 5
// 197.602 us; speedup vs baseline: 4.6501x; 2.1320x over previous
//
#include <hip/hip_runtime.h>

typedef __bf16 bf16x8 __attribute__((ext_vector_type(8)));
typedef float floatx4 __attribute__((ext_vector_type(4)));

#define XS 136    // LDS row stride in bf16 elements (272 B -> 2-way bank aliasing = free)
#define ROWS 64   // rows per block

__device__ __forceinline__ unsigned short f32_bf16(float f) {
    union { float f; unsigned int u; } c; c.f = f;
    return (unsigned short)((c.u + 0x7fffu + ((c.u >> 16) & 1u)) >> 16);  // RNE, finite inputs
}

// w1 -> MFMA B-fragment order, hidden-col mapping h(nt,l15) = l15*32 + nt.
// frag f = (e*32+nt)*4+ks ; lane (quad,l15) holds B[k=quad*8+j][n=l15] = w1[e][h][k]
__global__ __launch_bounds__(256) void prep_w1_frag(const float* __restrict__ w1,
                                                    unsigned short* __restrict__ wbf) {
    int g    = blockIdx.x * 256 + threadIdx.x;   // 64 blocks -> 16384 threads
    int lane = g & 63;
    int frag = g >> 6;                            // 0..255
    int ks   = frag & 3;
    int nt   = (frag >> 2) & 31;
    int e    = frag >> 7;
    int l15  = lane & 15;
    int quad = lane >> 4;
    int h    = l15 * 32 + nt;
    const float* src = w1 + ((e * 512 + h) * 128 + ks * 32 + quad * 8);
    unsigned short* dst = wbf + (long)g * 8;      // 16 B/lane, contiguous per wave
    #pragma unroll
    for (int j = 0; j < 8; ++j) dst[j] = f32_bf16(src[j]);
}

// One workgroup = 64 rows x all 1024 hidden cols. Wave w: expert e = w>>1,
// nt-half slice = w&1, 4 register-resident m-tiles.
// VGPR cap lesson (rounds 1-2): on this toolchain __launch_bounds__(256,N)
// empirically caps usable VGPRs at 256/N -> (256,2) was a HARD 128 cap and
// the afrag live set (~150) spilled to scratch (834 MB scratch writes).
// Plain __launch_bounds__(256): no min-waves constraint -> allocator free;
// afrag[4][4]=64 + outp[4][4][2]=32 + weights 16 + addressing ~ 150 fits
// with no spill; occupancy comes naturally (~3 waves/SIMD = 12 waves/CU,
// LDS 19.7 KB not a binder). No explicit prefetch (overlapping live ranges
// forced the round-2 spill; compiler hoists loads itself when regs allow).
__global__ __launch_bounds__(256) void moe_fused(
    const float* __restrict__ x,
    const unsigned short* __restrict__ wbf,   // fragment-ordered bf16 w1
    const float* __restrict__ b1,             // [2][512]
    const float* __restrict__ w2,             // [2][2][512]
    const float* __restrict__ b2,             // [2][2]
    const float* __restrict__ protos,         // [2][128]
    float* __restrict__ out)                  // [B][2]
{
    __shared__ unsigned short xs[ROWS * XS];  // 17408 B
    __shared__ float out_s[2][ROWS][2][2];    // [slice][row][e][o]  2048 B
    __shared__ int   t_s[ROWS];               // 256 B  -> 19712 B total

    const int tid   = threadIdx.x;
    const int lane  = tid & 63;
    const int wave  = tid >> 6;
    const int quad  = lane >> 4;
    const int l15   = lane & 15;
    const int slice = wave & 1;               // nt-half 0/1
    const int e     = wave >> 1;              // expert
    const long rowbase = (long)blockIdx.x * ROWS;

    // ---- routing: t = (d1 < d0) via sign of sum_c (p0-p1)*(0.5*(p0+p1)-x), fp64 ----
    if (tid < 2 * ROWS) {
        int r   = tid >> 1;
        int sub = tid & 1;
        const float* xr = x + (rowbase + r) * 128 + sub * 64;
        const float* p0 = protos + sub * 64;
        const float* p1 = protos + 128 + sub * 64;
        double acc = 0.0;
        #pragma unroll
        for (int k = 0; k < 16; ++k) {
            float4 xv = *(const float4*)(xr + k * 4);
            float4 a  = *(const float4*)(p0 + k * 4);
            float4 b  = *(const float4*)(p1 + k * 4);
            acc += ((double)a.x - b.x) * (0.5 * ((double)a.x + b.x) - xv.x);
            acc += ((double)a.y - b.y) * (0.5 * ((double)a.y + b.y) - xv.y);
            acc += ((double)a.z - b.z) * (0.5 * ((double)a.z + b.z) - xv.z);
            acc += ((double)a.w - b.w) * (0.5 * ((double)a.w + b.w) - xv.w);
        }
        acc += __shfl_xor(acc, 1);
        if (sub == 0) t_s[r] = (acc > 0.0) ? 1 : 0;   // tie -> expert 0 (numpy argmin)
    }

    // ---- stage x tile: coalesced float4 global reads -> bf16 LDS ----
    for (int i = tid; i < ROWS * 32; i += 256) {
        int r  = i >> 5;
        int c4 = (i & 31) * 4;
        float4 v = *(const float4*)(x + (rowbase + r) * 128 + c4);
        ushort4 p;
        p.x = f32_bf16(v.x); p.y = f32_bf16(v.y);
        p.z = f32_bf16(v.z); p.w = f32_bf16(v.w);
        *(ushort4*)&xs[r * XS + c4] = p;
    }
    __syncthreads();

    // ---- A fragments: 4 m-tiles x 4 k-steps, register-resident (one-time LDS read) ----
    // A-operand layout: A[m = lane&15][k = quad*8 + j]
    bf16x8 afrag[4][4];
    #pragma unroll
    for (int mt = 0; mt < 4; ++mt) {
        int r = mt * 16 + l15;
        #pragma unroll
        for (int ks = 0; ks < 4; ++ks)
            afrag[mt][ks] = *(const bf16x8*)&xs[r * XS + ks * 32 + quad * 8];
    }

    float outp[4][4][2] = {};   // [m-tile][reg(row)][o] layer-2 partials

    // ---- main loop: 16 n-tiles (this wave's expert + nt-half), all frags read once ----
    const bf16x8* wb8 = (const bf16x8*)wbf + (long)((e * 32 + slice * 16) * 4) * 64 + lane;
    const int    coff = e * 512 + l15 * 32 + slice * 16;
    const float* b1p  = b1 + coff;
    const float* w2ap = w2 + e * 1024 + l15 * 32 + slice * 16;
    const float* w2bp = w2ap + 512;
    for (int nt = 0; nt < 16; ++nt) {
        const bf16x8* wp = wb8 + nt * 256;
        bf16x8 bf0 = wp[0];
        bf16x8 bf1 = wp[64];
        bf16x8 bf2 = wp[128];
        bf16x8 bf3 = wp[192];
        float bb  = b1p[nt];
        float w2a = w2ap[nt];
        float w2b = w2bp[nt];
        #pragma unroll
        for (int mt = 0; mt < 4; ++mt) {
            floatx4 c = {bb, bb, bb, bb};   // bias folded into accumulator init
            c = __builtin_amdgcn_mfma_f32_16x16x32_bf16(afrag[mt][0], bf0, c, 0, 0, 0);
            c = __builtin_amdgcn_mfma_f32_16x16x32_bf16(afrag[mt][1], bf1, c, 0, 0, 0);
            c = __builtin_amdgcn_mfma_f32_16x16x32_bf16(afrag[mt][2], bf2, c, 0, 0, 0);
            c = __builtin_amdgcn_mfma_f32_16x16x32_bf16(afrag[mt][3], bf3, c, 0, 0, 0);
            #pragma unroll
            for (int rg = 0; rg < 4; ++rg) {
                float h = fmaxf(c[rg], 0.0f);
                outp[mt][rg][0] = fmaf(h, w2a, outp[mt][rg][0]);
                outp[mt][rg][1] = fmaf(h, w2b, outp[mt][rg][1]);
            }
        }
    }

    // ---- reduce layer-2 partials across the 16 column-lanes, write slice buffer ----
    #pragma unroll
    for (int mt = 0; mt < 4; ++mt)
        #pragma unroll
        for (int rg = 0; rg < 4; ++rg) {
            float v0 = outp[mt][rg][0];
            float v1 = outp[mt][rg][1];
            v0 += __shfl_xor(v0, 1);  v1 += __shfl_xor(v1, 1);
            v0 += __shfl_xor(v0, 2);  v1 += __shfl_xor(v1, 2);
            v0 += __shfl_xor(v0, 4);  v1 += __shfl_xor(v1, 4);
            v0 += __shfl_xor(v0, 8);  v1 += __shfl_xor(v1, 8);
            if (l15 == 0) {
                int r = mt * 16 + quad * 4 + rg;   // C/D: row = quad*4 + reg
                out_s[slice][r][e][0] = v0;
                out_s[slice][r][e][1] = v1;
            }
        }
    __syncthreads();

    // ---- select expert per row, combine nt-halves, add b2, coalesced store ----
    if (tid < 2 * ROWS) {
        int r  = tid >> 1;
        int o  = tid & 1;
        int te = t_s[r];
        out[(rowbase + r) * 2 + o] =
            out_s[0][r][te][o] + out_s[1][r][te][o] + b2[te * 2 + o];
    }
}

extern "C" void kernel_launch(void* const* d_in, const int* in_sizes, int n_in,
                              void* d_out, int out_size, void* d_ws, size_t ws_size,
                              hipStream_t stream) {
    const float* x      = (const float*)d_in[0];
    const float* w1     = (const float*)d_in[1];
    const float* b1     = (const float*)d_in[2];
    const float* w2     = (const float*)d_in[3];
    const float* b2     = (const float*)d_in[4];
    const float* protos = (const float*)d_in[5];
    float* out = (float*)d_out;
    unsigned short* wbf = (unsigned short*)d_ws;   // 256 KiB bf16 fragment-ordered w1

    prep_w1_frag<<<dim3(64), dim3(256), 0, stream>>>(w1, wbf);
    moe_fused<<<dim3(2048), dim3(256), 0, stream>>>(x, wbf, b1, w2, b2, protos, out);
}